// Round 1
// baseline (174.607 us; speedup 1.0000x reference)
//
#include <hip/hip_runtime.h>
#include <math.h>

#define BATCH      2048
#define IN_DIM     784
#define HIDDEN     512
#define STYLE      128
#define NUM_LABELS 10
#define FC1_STRIDE ((IN_DIM + 1) * HIDDEN)   // 785*512 = 401920
#define FC2_STRIDE ((HIDDEN + 1) * STYLE)    // 513*128 = 65664

#define TB        64    // rows per tile
#define MAX_TILES 48    // >= max possible sum(ceil(c_L/64)) = 41
#define KC        16

// meta (int) layout in d_ws:
//  [0..9]   counts
//  [10..19] cursors
//  [20..30] offsets (exclusive prefix, 11 entries)
//  [31]     ntiles
//  [32..32+3*MAX_TILES) tile table: (label, pstart, nrows)
//  [176..176+2048)      perm
// h1p (float[2048*512]) at byte offset 16384
#define META_CURS   10
#define META_OFFS   20
#define META_NTILES 31
#define META_TILES  32
#define META_PERM   176
#define H1P_BYTE_OFF 16384

__global__ void k_setup(const int* __restrict__ m, int* __restrict__ meta) {
    __shared__ int cnt[NUM_LABELS];
    int tid = threadIdx.x;
    if (tid < NUM_LABELS) cnt[tid] = 0;
    __syncthreads();
    for (int b = tid; b < BATCH; b += blockDim.x)
        atomicAdd(&cnt[m[b]], 1);
    __syncthreads();
    if (tid == 0) {
        int off = 0, idx = 0;
        for (int L = 0; L < NUM_LABELS; ++L) {
            int c = cnt[L];
            meta[L] = c;                 // counts
            meta[META_CURS + L] = 0;     // cursors
            meta[META_OFFS + L] = off;   // offsets
            for (int t = 0; t < c; t += TB) {
                meta[META_TILES + idx * 3 + 0] = L;
                meta[META_TILES + idx * 3 + 1] = off + t;
                meta[META_TILES + idx * 3 + 2] = min(TB, c - t);
                ++idx;
            }
            off += c;
        }
        meta[META_OFFS + NUM_LABELS] = off;
        meta[META_NTILES] = idx;
        for (int t = idx; t < MAX_TILES; ++t) {
            meta[META_TILES + t * 3 + 0] = 0;
            meta[META_TILES + t * 3 + 1] = 0;
            meta[META_TILES + t * 3 + 2] = 0;
        }
    }
}

__global__ void k_scatter(const int* __restrict__ m, int* __restrict__ meta) {
    int b = blockIdx.x * blockDim.x + threadIdx.x;
    if (b >= BATCH) return;
    int L = m[b];
    int r = atomicAdd(&meta[META_CURS + L], 1);
    meta[META_PERM + meta[META_OFFS + L] + r] = b;
}

// 64x64 fp32 tile GEMM: h1p[pstart+i][j] = relu(sum_k x[rows[i]][k]*W1[k][j] + b1[j])
__launch_bounds__(256)
__global__ void k_fc1(const float* __restrict__ x, const float* __restrict__ fc1t,
                      const int* __restrict__ meta, float* __restrict__ h1p) {
    int t = blockIdx.x;
    if (t >= meta[META_NTILES]) return;
    const int L      = meta[META_TILES + 3 * t + 0];
    const int pstart = meta[META_TILES + 3 * t + 1];
    const int nrows  = meta[META_TILES + 3 * t + 2];
    const int col0   = blockIdx.y * 64;
    const float* __restrict__ W = fc1t + (size_t)L * FC1_STRIDE;

    __shared__ int   rows[TB];
    __shared__ float As[KC][TB + 4];   // +4 pad: keeps float4 reads aligned, breaks conflicts
    __shared__ float Bs[KC][64];

    const int tid = threadIdx.x;
    if (tid < TB) rows[tid] = (tid < nrows) ? meta[META_PERM + pstart + tid] : -1;
    __syncthreads();

    const int tr = tid >> 4, tc = tid & 15;       // 16x16 thread grid, 4x4 micro-tile
    const int ai = tid >> 2, ak = (tid & 3) * 4;  // A staging: row 0..63, k 0..12
    const int bk = tid >> 4, bj = (tid & 15) * 4; // B staging: k 0..15, col 0..60

    const int arow = rows[ai];
    const float* __restrict__ xrow = x + (size_t)(arow < 0 ? 0 : arow) * IN_DIM;
    const bool aval = (arow >= 0);

    float acc[4][4] = {};

    for (int k0 = 0; k0 < IN_DIM; k0 += KC) {
        float4 av = make_float4(0.f, 0.f, 0.f, 0.f);
        if (aval) av = *(const float4*)(xrow + k0 + ak);
        As[ak + 0][ai] = av.x; As[ak + 1][ai] = av.y;
        As[ak + 2][ai] = av.z; As[ak + 3][ai] = av.w;
        float4 bv = *(const float4*)(W + (size_t)(k0 + bk) * HIDDEN + col0 + bj);
        *(float4*)&Bs[bk][bj] = bv;
        __syncthreads();
#pragma unroll
        for (int kk = 0; kk < KC; ++kk) {
            float4 a = *(const float4*)&As[kk][tr * 4];
            float4 b = *(const float4*)&Bs[kk][tc * 4];
            acc[0][0] = fmaf(a.x, b.x, acc[0][0]); acc[0][1] = fmaf(a.x, b.y, acc[0][1]);
            acc[0][2] = fmaf(a.x, b.z, acc[0][2]); acc[0][3] = fmaf(a.x, b.w, acc[0][3]);
            acc[1][0] = fmaf(a.y, b.x, acc[1][0]); acc[1][1] = fmaf(a.y, b.y, acc[1][1]);
            acc[1][2] = fmaf(a.y, b.z, acc[1][2]); acc[1][3] = fmaf(a.y, b.w, acc[1][3]);
            acc[2][0] = fmaf(a.z, b.x, acc[2][0]); acc[2][1] = fmaf(a.z, b.y, acc[2][1]);
            acc[2][2] = fmaf(a.z, b.z, acc[2][2]); acc[2][3] = fmaf(a.z, b.w, acc[2][3]);
            acc[3][0] = fmaf(a.w, b.x, acc[3][0]); acc[3][1] = fmaf(a.w, b.y, acc[3][1]);
            acc[3][2] = fmaf(a.w, b.z, acc[3][2]); acc[3][3] = fmaf(a.w, b.w, acc[3][3]);
        }
        __syncthreads();
    }

    const float4 bias = *(const float4*)(W + (size_t)IN_DIM * HIDDEN + col0 + tc * 4);
#pragma unroll
    for (int i = 0; i < 4; ++i) {
        int r = tr * 4 + i;
        if (r < nrows) {
            float4 v;
            v.x = fmaxf(acc[i][0] + bias.x, 0.f);
            v.y = fmaxf(acc[i][1] + bias.y, 0.f);
            v.z = fmaxf(acc[i][2] + bias.z, 0.f);
            v.w = fmaxf(acc[i][3] + bias.w, 0.f);
            *(float4*)(h1p + (size_t)(pstart + r) * HIDDEN + col0 + tc * 4) = v;
        }
    }
}

// 64x64 fp32 tile GEMM: out[rows[i]][j] = sigmoid(sum_k h1p[pstart+i][k]*W2[k][j] + b2[j])
__launch_bounds__(256)
__global__ void k_fc2(const float* __restrict__ h1p, const float* __restrict__ fc2t,
                      const int* __restrict__ meta, float* __restrict__ out) {
    int t = blockIdx.x;
    if (t >= meta[META_NTILES]) return;
    const int L      = meta[META_TILES + 3 * t + 0];
    const int pstart = meta[META_TILES + 3 * t + 1];
    const int nrows  = meta[META_TILES + 3 * t + 2];
    const int col0   = blockIdx.y * 64;
    const float* __restrict__ W = fc2t + (size_t)L * FC2_STRIDE;

    __shared__ int   rows[TB];
    __shared__ float As[KC][TB + 4];
    __shared__ float Bs[KC][64];

    const int tid = threadIdx.x;
    if (tid < TB) rows[tid] = (tid < nrows) ? meta[META_PERM + pstart + tid] : -1;
    __syncthreads();

    const int tr = tid >> 4, tc = tid & 15;
    const int ai = tid >> 2, ak = (tid & 3) * 4;
    const int bk = tid >> 4, bj = (tid & 15) * 4;
    const bool aval = (ai < nrows);

    float acc[4][4] = {};

    for (int k0 = 0; k0 < HIDDEN; k0 += KC) {
        float4 av = make_float4(0.f, 0.f, 0.f, 0.f);
        if (aval) av = *(const float4*)(h1p + (size_t)(pstart + ai) * HIDDEN + k0 + ak);
        As[ak + 0][ai] = av.x; As[ak + 1][ai] = av.y;
        As[ak + 2][ai] = av.z; As[ak + 3][ai] = av.w;
        float4 bv = *(const float4*)(W + (size_t)(k0 + bk) * STYLE + col0 + bj);
        *(float4*)&Bs[bk][bj] = bv;
        __syncthreads();
#pragma unroll
        for (int kk = 0; kk < KC; ++kk) {
            float4 a = *(const float4*)&As[kk][tr * 4];
            float4 b = *(const float4*)&Bs[kk][tc * 4];
            acc[0][0] = fmaf(a.x, b.x, acc[0][0]); acc[0][1] = fmaf(a.x, b.y, acc[0][1]);
            acc[0][2] = fmaf(a.x, b.z, acc[0][2]); acc[0][3] = fmaf(a.x, b.w, acc[0][3]);
            acc[1][0] = fmaf(a.y, b.x, acc[1][0]); acc[1][1] = fmaf(a.y, b.y, acc[1][1]);
            acc[1][2] = fmaf(a.y, b.z, acc[1][2]); acc[1][3] = fmaf(a.y, b.w, acc[1][3]);
            acc[2][0] = fmaf(a.z, b.x, acc[2][0]); acc[2][1] = fmaf(a.z, b.y, acc[2][1]);
            acc[2][2] = fmaf(a.z, b.z, acc[2][2]); acc[2][3] = fmaf(a.z, b.w, acc[2][3]);
            acc[3][0] = fmaf(a.w, b.x, acc[3][0]); acc[3][1] = fmaf(a.w, b.y, acc[3][1]);
            acc[3][2] = fmaf(a.w, b.z, acc[3][2]); acc[3][3] = fmaf(a.w, b.w, acc[3][3]);
        }
        __syncthreads();
    }

    const float4 bias = *(const float4*)(W + (size_t)HIDDEN * STYLE + col0 + tc * 4);
#pragma unroll
    for (int i = 0; i < 4; ++i) {
        int r = tr * 4 + i;
        if (r < nrows) {
            int orow = rows[r];
            float4 v;
            v.x = 1.f / (1.f + __expf(-(acc[i][0] + bias.x)));
            v.y = 1.f / (1.f + __expf(-(acc[i][1] + bias.y)));
            v.z = 1.f / (1.f + __expf(-(acc[i][2] + bias.z)));
            v.w = 1.f / (1.f + __expf(-(acc[i][3] + bias.w)));
            *(float4*)(out + (size_t)orow * STYLE + col0 + tc * 4) = v;
        }
    }
}

// Fallback (ws too small): one block per batch row, fused, slow but correct.
__launch_bounds__(256)
__global__ void k_naive(const float* __restrict__ x, const int* __restrict__ m,
                        const float* __restrict__ fc1t, const float* __restrict__ fc2t,
                        float* __restrict__ out) {
    __shared__ float xs[IN_DIM];
    __shared__ float h1[HIDDEN];
    const int b = blockIdx.x;
    const int tid = threadIdx.x;
    const int L = m[b];
    for (int k = tid; k < IN_DIM; k += 256) xs[k] = x[(size_t)b * IN_DIM + k];
    __syncthreads();
    const float* __restrict__ W1 = fc1t + (size_t)L * FC1_STRIDE;
    for (int j = tid; j < HIDDEN; j += 256) {
        float acc = W1[(size_t)IN_DIM * HIDDEN + j];
        for (int k = 0; k < IN_DIM; ++k) acc = fmaf(xs[k], W1[(size_t)k * HIDDEN + j], acc);
        h1[j] = fmaxf(acc, 0.f);
    }
    __syncthreads();
    const float* __restrict__ W2 = fc2t + (size_t)L * FC2_STRIDE;
    for (int j = tid; j < STYLE; j += 256) {
        float acc = W2[(size_t)HIDDEN * STYLE + j];
        for (int k = 0; k < HIDDEN; ++k) acc = fmaf(h1[k], W2[(size_t)k * STYLE + j], acc);
        out[(size_t)b * STYLE + j] = 1.f / (1.f + __expf(-acc));
    }
}

extern "C" void kernel_launch(void* const* d_in, const int* in_sizes, int n_in,
                              void* d_out, int out_size, void* d_ws, size_t ws_size,
                              hipStream_t stream) {
    const float* x    = (const float*)d_in[0];
    const int*   m    = (const int*)d_in[1];
    const float* fc1t = (const float*)d_in[2];
    const float* fc2t = (const float*)d_in[3];
    float* out = (float*)d_out;

    const size_t need = H1P_BYTE_OFF + (size_t)BATCH * HIDDEN * sizeof(float);
    if (ws_size >= need) {
        int*   meta = (int*)d_ws;
        float* h1p  = (float*)((char*)d_ws + H1P_BYTE_OFF);
        k_setup<<<1, 256, 0, stream>>>(m, meta);
        k_scatter<<<(BATCH + 255) / 256, 256, 0, stream>>>(m, meta);
        k_fc1<<<dim3(MAX_TILES, HIDDEN / 64), 256, 0, stream>>>(x, fc1t, meta, h1p);
        k_fc2<<<dim3(MAX_TILES, STYLE / 64), 256, 0, stream>>>(h1p, fc2t, meta, out);
    } else {
        k_naive<<<BATCH, 256, 0, stream>>>(x, m, fc1t, fc2t, out);
    }
}

// Round 2
// 122.127 us; speedup vs baseline: 1.4297x; 1.4297x over previous
//
#include <hip/hip_runtime.h>
#include <hip/hip_bf16.h>
#include <math.h>

#define BATCH      2048
#define IN_DIM     784
#define HIDDEN     512
#define STYLE      128
#define NUM_LABELS 10
#define FC1_STRIDE ((IN_DIM + 1) * HIDDEN)   // 785*512 = 401920
#define FC2_STRIDE ((HIDDEN + 1) * STYLE)    // 513*128 = 65664
#define KP1        800                        // IN_DIM padded to mult of 32

#define TB        64
#define MAX_TILES 48    // >= max possible sum(ceil(c_L/64)) = 41
#define BK        32

// ---- meta (int) layout at d_ws byte 0 ----
#define META_NTILES 31
#define META_TILES  32                        // 3 ints per tile: label,pstart,nrows
#define META_PERM   176

// ---- bf16 workspace layout (byte offsets) ----
#define XB_OFF   16384ULL                              // [2048][800] bf16
#define W1B_OFF  (XB_OFF  + 2048ULL*KP1*2)             // [10][512][800] bf16 ([L][n][k])
#define W2B_OFF  (W1B_OFF + 10ULL*512*KP1*2)           // [10][128][512] bf16 ([L][n][k])
#define H1B_OFF  (W2B_OFF + 10ULL*128*512*2)           // [2048][512] bf16 (permuted rows)
#define BF16_NEED (H1B_OFF + 2048ULL*512*2)            // ~14.9 MB

// fp32-fallback layout (round-1 kernel set)
#define H1P_BYTE_OFF 16384ULL
#define FP32_NEED (H1P_BYTE_OFF + 2048ULL*512*4)

typedef short short8  __attribute__((ext_vector_type(8)));
typedef float float4e __attribute__((ext_vector_type(4)));

__device__ __forceinline__ ushort f2b(float v) {
    __hip_bfloat16 h = __float2bfloat16(v);
    return *reinterpret_cast<ushort*>(&h);
}

// ---------- meta: histogram + prefix + scatter + tile table, one block ----------
__global__ void k_meta(const int* __restrict__ m, int* __restrict__ meta) {
    __shared__ int cnt[NUM_LABELS], curs[NUM_LABELS], offs[NUM_LABELS + 1];
    __shared__ int permS[BATCH];
    const int tid = threadIdx.x;
    if (tid < NUM_LABELS) { cnt[tid] = 0; curs[tid] = 0; }
    __syncthreads();
    for (int b = tid; b < BATCH; b += 256) atomicAdd(&cnt[m[b]], 1);
    __syncthreads();
    if (tid == 0) {
        int off = 0;
        for (int L = 0; L < NUM_LABELS; ++L) { offs[L] = off; off += cnt[L]; }
        offs[NUM_LABELS] = off;
    }
    __syncthreads();
    for (int b = tid; b < BATCH; b += 256) {
        int L = m[b];
        int r = atomicAdd(&curs[L], 1);
        permS[offs[L] + r] = b;
    }
    __syncthreads();
    for (int i = tid; i < BATCH; i += 256) meta[META_PERM + i] = permS[i];
    if (tid == 0) {
        int idx = 0;
        for (int L = 0; L < NUM_LABELS; ++L) {
            int c = cnt[L], off = offs[L];
            for (int t = 0; t < c; t += TB) {
                meta[META_TILES + idx * 3 + 0] = L;
                meta[META_TILES + idx * 3 + 1] = off + t;
                meta[META_TILES + idx * 3 + 2] = min(TB, c - t);
                ++idx;
            }
        }
        meta[META_NTILES] = idx;
    }
}

// ---------- convert x -> bf16, pad K to 800 ----------
__global__ void k_cvt_x(const float* __restrict__ x, ushort* __restrict__ xb) {
    const int row = blockIdx.y;
    const int k = blockIdx.x * 256 + threadIdx.x;
    if (k < KP1)
        xb[(size_t)row * KP1 + k] = (k < IN_DIM) ? f2b(x[(size_t)row * IN_DIM + k]) : 0;
}

// ---------- transpose+convert: dst[L][n][Kpad] (bf16) = src[L][k][n] (f32) ----------
__global__ void k_cvtT(const float* __restrict__ src, ushort* __restrict__ dst,
                       int Kvalid, int Kpad, int N,
                       size_t srcLstride, size_t dstLstride) {
    __shared__ float tile[32][33];
    const int k0 = blockIdx.x * 32, n0 = blockIdx.y * 32, L = blockIdx.z;
    const int tx = threadIdx.x, ty = threadIdx.y;   // 32 x 8
    for (int r = ty; r < 32; r += 8) {
        int k = k0 + r;
        tile[r][tx] = (k < Kvalid) ? src[(size_t)L * srcLstride + (size_t)k * N + n0 + tx] : 0.f;
    }
    __syncthreads();
    for (int r = ty; r < 32; r += 8) {
        int n = n0 + r;
        dst[(size_t)L * dstLstride + (size_t)n * Kpad + k0 + tx] = f2b(tile[tx][r]);
    }
}

// ---------- fc1: h1b[pstart+i][j] = relu( x[rows[i]]·W1 + b1 )  (bf16 MFMA) ----------
__launch_bounds__(256)
__global__ void k_fc1m(const ushort* __restrict__ xb, const ushort* __restrict__ w1b,
                       const float* __restrict__ fc1t, const int* __restrict__ meta,
                       ushort* __restrict__ h1b) {
    const int t = blockIdx.x;
    if (t >= meta[META_NTILES]) return;
    const int L      = meta[META_TILES + 3 * t + 0];
    const int pstart = meta[META_TILES + 3 * t + 1];
    const int nrows  = meta[META_TILES + 3 * t + 2];
    const int col0   = blockIdx.y * 64;
    const ushort* __restrict__ W = w1b + (size_t)L * 512 * KP1;

    __shared__ int rows[TB];
    __shared__ __align__(16) ushort As[64][40];   // [row][k], stride 40 (80B) breaks conflicts
    __shared__ __align__(16) ushort Bs[64][40];   // [n][k]

    const int tid = threadIdx.x;
    if (tid < TB) rows[tid] = (tid < nrows) ? meta[META_PERM + pstart + tid] : -1;
    __syncthreads();

    const int sr = tid >> 2, sc = tid & 3;        // staging: row 0..63, 16B chunk 0..3
    const int lane = tid & 63, wv = tid >> 6;
    const int qd = lane >> 4, ln16 = lane & 15;

    const int arow = rows[sr];
    const uint4* __restrict__ agp = (arow >= 0) ? (const uint4*)(xb + (size_t)arow * KP1) : nullptr;
    const uint4* __restrict__ bgp = (const uint4*)(W + (size_t)(col0 + sr) * KP1);

    float4e acc[4] = {};

    for (int k0 = 0; k0 < KP1; k0 += BK) {
        uint4 av = make_uint4(0u, 0u, 0u, 0u);
        if (agp) av = agp[(k0 >> 3) + sc];
        *(uint4*)&As[sr][sc * 8] = av;
        *(uint4*)&Bs[sr][sc * 8] = bgp[(k0 >> 3) + sc];
        __syncthreads();
        short8 a = *(const short8*)&As[wv * 16 + ln16][qd * 8];
#pragma unroll
        for (int nt = 0; nt < 4; ++nt) {
            short8 b = *(const short8*)&Bs[nt * 16 + ln16][qd * 8];
            acc[nt] = __builtin_amdgcn_mfma_f32_16x16x32_bf16(a, b, acc[nt], 0, 0, 0);
        }
        __syncthreads();
    }

    const float* __restrict__ bias = fc1t + (size_t)L * FC1_STRIDE + (size_t)IN_DIM * HIDDEN + col0;
#pragma unroll
    for (int nt = 0; nt < 4; ++nt) {
        const int c = nt * 16 + ln16;
        const float bs = bias[c];
#pragma unroll
        for (int i = 0; i < 4; ++i) {
            const int r = wv * 16 + qd * 4 + i;
            if (r < nrows)
                h1b[(size_t)(pstart + r) * HIDDEN + col0 + c] = f2b(fmaxf(acc[nt][i] + bs, 0.f));
        }
    }
}

// ---------- fc2: out[rows[i]][j] = sigmoid( h1[i]·W2 + b2 )  (bf16 MFMA) ----------
__launch_bounds__(256)
__global__ void k_fc2m(const ushort* __restrict__ h1b, const ushort* __restrict__ w2b,
                       const float* __restrict__ fc2t, const int* __restrict__ meta,
                       float* __restrict__ out) {
    const int t = blockIdx.x;
    if (t >= meta[META_NTILES]) return;
    const int L      = meta[META_TILES + 3 * t + 0];
    const int pstart = meta[META_TILES + 3 * t + 1];
    const int nrows  = meta[META_TILES + 3 * t + 2];
    const int col0   = blockIdx.y * 64;
    const ushort* __restrict__ W = w2b + (size_t)L * 128 * 512;

    __shared__ int rows[TB];
    __shared__ __align__(16) ushort As[64][40];
    __shared__ __align__(16) ushort Bs[64][40];

    const int tid = threadIdx.x;
    if (tid < TB) rows[tid] = (tid < nrows) ? meta[META_PERM + pstart + tid] : -1;
    __syncthreads();

    const int sr = tid >> 2, sc = tid & 3;
    const int lane = tid & 63, wv = tid >> 6;
    const int qd = lane >> 4, ln16 = lane & 15;

    const bool aval = (sr < nrows);
    const uint4* __restrict__ agp = (const uint4*)(h1b + (size_t)(pstart + (aval ? sr : 0)) * HIDDEN);
    const uint4* __restrict__ bgp = (const uint4*)(W + (size_t)(col0 + sr) * 512);

    float4e acc[4] = {};

    for (int k0 = 0; k0 < HIDDEN; k0 += BK) {
        uint4 av = make_uint4(0u, 0u, 0u, 0u);
        if (aval) av = agp[(k0 >> 3) + sc];
        *(uint4*)&As[sr][sc * 8] = av;
        *(uint4*)&Bs[sr][sc * 8] = bgp[(k0 >> 3) + sc];
        __syncthreads();
        short8 a = *(const short8*)&As[wv * 16 + ln16][qd * 8];
#pragma unroll
        for (int nt = 0; nt < 4; ++nt) {
            short8 b = *(const short8*)&Bs[nt * 16 + ln16][qd * 8];
            acc[nt] = __builtin_amdgcn_mfma_f32_16x16x32_bf16(a, b, acc[nt], 0, 0, 0);
        }
        __syncthreads();
    }

    const float* __restrict__ bias = fc2t + (size_t)L * FC2_STRIDE + (size_t)HIDDEN * STYLE + col0;
#pragma unroll
    for (int nt = 0; nt < 4; ++nt) {
        const int c = nt * 16 + ln16;
        const float bs = bias[c];
#pragma unroll
        for (int i = 0; i < 4; ++i) {
            const int r = wv * 16 + qd * 4 + i;
            if (r < nrows) {
                const int orow = rows[r];
                out[(size_t)orow * STYLE + col0 + c] = 1.f / (1.f + __expf(-(acc[nt][i] + bs)));
            }
        }
    }
}

// ================= fp32 fallback path (round-1 kernels) =================
#define KC 16
__global__ void k_setup(const int* __restrict__ m, int* __restrict__ meta) {
    __shared__ int cnt[NUM_LABELS];
    int tid = threadIdx.x;
    if (tid < NUM_LABELS) cnt[tid] = 0;
    __syncthreads();
    for (int b = tid; b < BATCH; b += blockDim.x) atomicAdd(&cnt[m[b]], 1);
    __syncthreads();
    if (tid == 0) {
        int off = 0, idx = 0;
        for (int L = 0; L < NUM_LABELS; ++L) {
            int c = cnt[L];
            meta[L] = c; meta[10 + L] = 0; meta[20 + L] = off;
            for (int t = 0; t < c; t += TB) {
                meta[META_TILES + idx * 3 + 0] = L;
                meta[META_TILES + idx * 3 + 1] = off + t;
                meta[META_TILES + idx * 3 + 2] = min(TB, c - t);
                ++idx;
            }
            off += c;
        }
        meta[30] = off; meta[META_NTILES] = idx;
        for (int t = idx; t < MAX_TILES; ++t) {
            meta[META_TILES + t * 3 + 0] = 0;
            meta[META_TILES + t * 3 + 1] = 0;
            meta[META_TILES + t * 3 + 2] = 0;
        }
    }
}
__global__ void k_scatter(const int* __restrict__ m, int* __restrict__ meta) {
    int b = blockIdx.x * blockDim.x + threadIdx.x;
    if (b >= BATCH) return;
    int L = m[b];
    int r = atomicAdd(&meta[10 + L], 1);
    meta[META_PERM + meta[20 + L] + r] = b;
}
__launch_bounds__(256)
__global__ void k_fc1(const float* __restrict__ x, const float* __restrict__ fc1t,
                      const int* __restrict__ meta, float* __restrict__ h1p) {
    int t = blockIdx.x;
    if (t >= meta[META_NTILES]) return;
    const int L = meta[META_TILES + 3 * t + 0], pstart = meta[META_TILES + 3 * t + 1],
              nrows = meta[META_TILES + 3 * t + 2], col0 = blockIdx.y * 64;
    const float* __restrict__ W = fc1t + (size_t)L * FC1_STRIDE;
    __shared__ int rows[TB];
    __shared__ float As[KC][TB + 4];
    __shared__ float Bs[KC][64];
    const int tid = threadIdx.x;
    if (tid < TB) rows[tid] = (tid < nrows) ? meta[META_PERM + pstart + tid] : -1;
    __syncthreads();
    const int tr = tid >> 4, tc = tid & 15;
    const int ai = tid >> 2, ak = (tid & 3) * 4;
    const int bk = tid >> 4, bj = (tid & 15) * 4;
    const int arow = rows[ai];
    const float* __restrict__ xrow = x + (size_t)(arow < 0 ? 0 : arow) * IN_DIM;
    const bool aval = (arow >= 0);
    float acc[4][4] = {};
    for (int k0 = 0; k0 < IN_DIM; k0 += KC) {
        float4 av = make_float4(0.f, 0.f, 0.f, 0.f);
        if (aval) av = *(const float4*)(xrow + k0 + ak);
        As[ak + 0][ai] = av.x; As[ak + 1][ai] = av.y; As[ak + 2][ai] = av.z; As[ak + 3][ai] = av.w;
        *(float4*)&Bs[bk][bj] = *(const float4*)(W + (size_t)(k0 + bk) * HIDDEN + col0 + bj);
        __syncthreads();
#pragma unroll
        for (int kk = 0; kk < KC; ++kk) {
            float4 a = *(const float4*)&As[kk][tr * 4];
            float4 b = *(const float4*)&Bs[kk][tc * 4];
#pragma unroll
            for (int i = 0; i < 4; ++i) {
                float av2 = (&a.x)[i];
                acc[i][0] = fmaf(av2, b.x, acc[i][0]); acc[i][1] = fmaf(av2, b.y, acc[i][1]);
                acc[i][2] = fmaf(av2, b.z, acc[i][2]); acc[i][3] = fmaf(av2, b.w, acc[i][3]);
            }
        }
        __syncthreads();
    }
    const float4 bias = *(const float4*)(W + (size_t)IN_DIM * HIDDEN + col0 + tc * 4);
#pragma unroll
    for (int i = 0; i < 4; ++i) {
        int r = tr * 4 + i;
        if (r < nrows) {
            float4 v;
            v.x = fmaxf(acc[i][0] + bias.x, 0.f); v.y = fmaxf(acc[i][1] + bias.y, 0.f);
            v.z = fmaxf(acc[i][2] + bias.z, 0.f); v.w = fmaxf(acc[i][3] + bias.w, 0.f);
            *(float4*)(h1p + (size_t)(pstart + r) * HIDDEN + col0 + tc * 4) = v;
        }
    }
}
__launch_bounds__(256)
__global__ void k_fc2(const float* __restrict__ h1p, const float* __restrict__ fc2t,
                      const int* __restrict__ meta, float* __restrict__ out) {
    int t = blockIdx.x;
    if (t >= meta[META_NTILES]) return;
    const int L = meta[META_TILES + 3 * t + 0], pstart = meta[META_TILES + 3 * t + 1],
              nrows = meta[META_TILES + 3 * t + 2], col0 = blockIdx.y * 64;
    const float* __restrict__ W = fc2t + (size_t)L * FC2_STRIDE;
    __shared__ int rows[TB];
    __shared__ float As[KC][TB + 4];
    __shared__ float Bs[KC][64];
    const int tid = threadIdx.x;
    if (tid < TB) rows[tid] = (tid < nrows) ? meta[META_PERM + pstart + tid] : -1;
    __syncthreads();
    const int tr = tid >> 4, tc = tid & 15;
    const int ai = tid >> 2, ak = (tid & 3) * 4;
    const int bk = tid >> 4, bj = (tid & 15) * 4;
    const bool aval = (ai < nrows);
    float acc[4][4] = {};
    for (int k0 = 0; k0 < HIDDEN; k0 += KC) {
        float4 av = make_float4(0.f, 0.f, 0.f, 0.f);
        if (aval) av = *(const float4*)(h1p + (size_t)(pstart + ai) * HIDDEN + k0 + ak);
        As[ak + 0][ai] = av.x; As[ak + 1][ai] = av.y; As[ak + 2][ai] = av.z; As[ak + 3][ai] = av.w;
        *(float4*)&Bs[bk][bj] = *(const float4*)(W + (size_t)(k0 + bk) * STYLE + col0 + bj);
        __syncthreads();
#pragma unroll
        for (int kk = 0; kk < KC; ++kk) {
            float4 a = *(const float4*)&As[kk][tr * 4];
            float4 b = *(const float4*)&Bs[kk][tc * 4];
#pragma unroll
            for (int i = 0; i < 4; ++i) {
                float av2 = (&a.x)[i];
                acc[i][0] = fmaf(av2, b.x, acc[i][0]); acc[i][1] = fmaf(av2, b.y, acc[i][1]);
                acc[i][2] = fmaf(av2, b.z, acc[i][2]); acc[i][3] = fmaf(av2, b.w, acc[i][3]);
            }
        }
        __syncthreads();
    }
    const float4 bias = *(const float4*)(W + (size_t)HIDDEN * STYLE + col0 + tc * 4);
#pragma unroll
    for (int i = 0; i < 4; ++i) {
        int r = tr * 4 + i;
        if (r < nrows) {
            int orow = rows[r];
            float4 v;
            v.x = 1.f / (1.f + __expf(-(acc[i][0] + bias.x)));
            v.y = 1.f / (1.f + __expf(-(acc[i][1] + bias.y)));
            v.z = 1.f / (1.f + __expf(-(acc[i][2] + bias.z)));
            v.w = 1.f / (1.f + __expf(-(acc[i][3] + bias.w)));
            *(float4*)(out + (size_t)orow * STYLE + col0 + tc * 4) = v;
        }
    }
}
__launch_bounds__(256)
__global__ void k_naive(const float* __restrict__ x, const int* __restrict__ m,
                        const float* __restrict__ fc1t, const float* __restrict__ fc2t,
                        float* __restrict__ out) {
    __shared__ float xs[IN_DIM];
    __shared__ float h1[HIDDEN];
    const int b = blockIdx.x, tid = threadIdx.x, L = m[b];
    for (int k = tid; k < IN_DIM; k += 256) xs[k] = x[(size_t)b * IN_DIM + k];
    __syncthreads();
    const float* __restrict__ W1 = fc1t + (size_t)L * FC1_STRIDE;
    for (int j = tid; j < HIDDEN; j += 256) {
        float acc = W1[(size_t)IN_DIM * HIDDEN + j];
        for (int k = 0; k < IN_DIM; ++k) acc = fmaf(xs[k], W1[(size_t)k * HIDDEN + j], acc);
        h1[j] = fmaxf(acc, 0.f);
    }
    __syncthreads();
    const float* __restrict__ W2 = fc2t + (size_t)L * FC2_STRIDE;
    for (int j = tid; j < STYLE; j += 256) {
        float acc = W2[(size_t)HIDDEN * STYLE + j];
        for (int k = 0; k < HIDDEN; ++k) acc = fmaf(h1[k], W2[(size_t)k * STYLE + j], acc);
        out[(size_t)b * STYLE + j] = 1.f / (1.f + __expf(-acc));
    }
}

extern "C" void kernel_launch(void* const* d_in, const int* in_sizes, int n_in,
                              void* d_out, int out_size, void* d_ws, size_t ws_size,
                              hipStream_t stream) {
    const float* x    = (const float*)d_in[0];
    const int*   m    = (const int*)d_in[1];
    const float* fc1t = (const float*)d_in[2];
    const float* fc2t = (const float*)d_in[3];
    float* out = (float*)d_out;

    if (ws_size >= BF16_NEED) {
        int*    meta = (int*)d_ws;
        ushort* xb   = (ushort*)((char*)d_ws + XB_OFF);
        ushort* w1b  = (ushort*)((char*)d_ws + W1B_OFF);
        ushort* w2b  = (ushort*)((char*)d_ws + W2B_OFF);
        ushort* h1b  = (ushort*)((char*)d_ws + H1B_OFF);

        k_meta<<<1, 256, 0, stream>>>(m, meta);
        k_cvt_x<<<dim3((KP1 + 255) / 256, BATCH), 256, 0, stream>>>(x, xb);
        k_cvtT<<<dim3(KP1 / 32, HIDDEN / 32, NUM_LABELS), dim3(32, 8), 0, stream>>>(
            fc1t, w1b, IN_DIM, KP1, HIDDEN, (size_t)FC1_STRIDE, (size_t)512 * KP1);
        k_cvtT<<<dim3(HIDDEN / 32, STYLE / 32, NUM_LABELS), dim3(32, 8), 0, stream>>>(
            fc2t, w2b, HIDDEN, HIDDEN, STYLE, (size_t)FC2_STRIDE, (size_t)128 * 512);
        k_fc1m<<<dim3(MAX_TILES, HIDDEN / 64), 256, 0, stream>>>(xb, w1b, fc1t, meta, h1b);
        k_fc2m<<<dim3(MAX_TILES, STYLE / 64), 256, 0, stream>>>(h1b, w2b, fc2t, meta, out);
    } else if (ws_size >= FP32_NEED) {
        int*   meta = (int*)d_ws;
        float* h1p  = (float*)((char*)d_ws + H1P_BYTE_OFF);
        k_setup<<<1, 256, 0, stream>>>(m, meta);
        k_scatter<<<(BATCH + 255) / 256, 256, 0, stream>>>(m, meta);
        k_fc1<<<dim3(MAX_TILES, HIDDEN / 64), 256, 0, stream>>>(x, fc1t, meta, h1p);
        k_fc2<<<dim3(MAX_TILES, STYLE / 64), 256, 0, stream>>>(h1p, fc2t, meta, out);
    } else {
        k_naive<<<BATCH, 256, 0, stream>>>(x, m, fc1t, fc2t, out);
    }
}

// Round 3
// 106.964 us; speedup vs baseline: 1.6324x; 1.1418x over previous
//
#include <hip/hip_runtime.h>
#include <hip/hip_bf16.h>
#include <math.h>

#define BATCH      2048
#define IN_DIM     784
#define HIDDEN     512
#define STYLE      128
#define NUM_LABELS 10
#define FC1_STRIDE ((IN_DIM + 1) * HIDDEN)   // 785*512
#define FC2_STRIDE ((HIDDEN + 1) * STYLE)    // 513*128
#define KP1        832                        // IN_DIM padded to mult of 64

#define TB        64
#define MAX_TILES 48    // >= max possible sum(ceil(c_L/64)) = 41
#define BK        64

// ---- meta (int) layout at d_ws byte 0 ----
#define META_NTILES 31
#define META_TILES  32     // 3 ints per tile: label,pstart,nrows
#define META_PERM   176

// ---- bf16 workspace layout (byte offsets) ----
#define W1B_OFF  16384ULL                               // [10][512][832] bf16 ([L][n][k])
#define W2B_OFF  (W1B_OFF + 10ULL*HIDDEN*KP1*2)         // [10][128][512] bf16 ([L][n][k])
#define H1B_OFF  (W2B_OFF + 10ULL*STYLE*HIDDEN*2)       // [2048][512] bf16 (permuted rows)
#define BF16_NEED (H1B_OFF + (size_t)BATCH*HIDDEN*2)    // ~11.9 MB

#define W1_KB 26                                        // 832/32
#define W1_NB 16                                        // 512/32
#define W2_KB 16                                        // 512/32
#define W2_NB 4                                         // 128/32
#define W1_BLOCKS (W1_KB*W1_NB*NUM_LABELS)              // 4160
#define W2_BLOCKS (W2_KB*W2_NB*NUM_LABELS)              // 640

typedef short short8  __attribute__((ext_vector_type(8)));
typedef float float4e __attribute__((ext_vector_type(4)));

__device__ __forceinline__ ushort f2b(float v) {
    __hip_bfloat16 h = __float2bfloat16(v);
    return *reinterpret_cast<ushort*>(&h);
}

// ---------- prep: block 0 = meta; rest = weight transpose+convert ----------
__global__ void k_prep(const int* __restrict__ m, const float* __restrict__ fc1t,
                       const float* __restrict__ fc2t, int* __restrict__ meta,
                       ushort* __restrict__ w1b, ushort* __restrict__ w2b) {
    const int tid = threadIdx.x;
    int bid = blockIdx.x;

    __shared__ int cnt[NUM_LABELS], curs[NUM_LABELS], offs[NUM_LABELS + 1];
    __shared__ int permS[BATCH];
    __shared__ float tile[32][33];

    if (bid == 0) {
        // ---- meta: histogram + prefix + scatter + tile table ----
        if (tid < NUM_LABELS) { cnt[tid] = 0; curs[tid] = 0; }
        __syncthreads();
        for (int b = tid; b < BATCH; b += 256) atomicAdd(&cnt[m[b]], 1);
        __syncthreads();
        if (tid == 0) {
            int off = 0;
            for (int L = 0; L < NUM_LABELS; ++L) { offs[L] = off; off += cnt[L]; }
            offs[NUM_LABELS] = off;
        }
        __syncthreads();
        for (int b = tid; b < BATCH; b += 256) {
            int L = m[b];
            int r = atomicAdd(&curs[L], 1);
            permS[offs[L] + r] = b;
        }
        __syncthreads();
        for (int i = tid; i < BATCH; i += 256) meta[META_PERM + i] = permS[i];
        if (tid == 0) {
            int idx = 0;
            for (int L = 0; L < NUM_LABELS; ++L) {
                int c = cnt[L], off = offs[L];
                for (int t = 0; t < c; t += TB) {
                    meta[META_TILES + idx * 3 + 0] = L;
                    meta[META_TILES + idx * 3 + 1] = off + t;
                    meta[META_TILES + idx * 3 + 2] = min(TB, c - t);
                    ++idx;
                }
            }
            meta[META_NTILES] = idx;
        }
        return;
    }

    // ---- transpose+convert: dst[L][n][Kpad] (bf16) = src[L][k][n] (f32) ----
    bid -= 1;
    const float* src; ushort* dst; int Kvalid, Kpad, N, kb, nb, L; size_t srcL, dstL;
    if (bid < W1_BLOCKS) {
        kb = bid % W1_KB; nb = (bid / W1_KB) % W1_NB; L = bid / (W1_KB * W1_NB);
        src = fc1t; dst = w1b; Kvalid = IN_DIM; Kpad = KP1; N = HIDDEN;
        srcL = FC1_STRIDE; dstL = (size_t)HIDDEN * KP1;
    } else {
        bid -= W1_BLOCKS;
        kb = bid % W2_KB; nb = (bid / W2_KB) % W2_NB; L = bid / (W2_KB * W2_NB);
        src = fc2t; dst = w2b; Kvalid = HIDDEN; Kpad = HIDDEN; N = STYLE;
        srcL = FC2_STRIDE; dstL = (size_t)STYLE * HIDDEN;
    }
    const int tx = tid & 31, ty = tid >> 5;
    const int k0 = kb * 32, n0 = nb * 32;
    for (int r = ty; r < 32; r += 8) {
        int k = k0 + r;
        tile[r][tx] = (k < Kvalid) ? src[(size_t)L * srcL + (size_t)k * N + n0 + tx] : 0.f;
    }
    __syncthreads();
    for (int r = ty; r < 32; r += 8) {
        int n = n0 + r;
        dst[(size_t)L * dstL + (size_t)n * Kpad + k0 + tx] = f2b(tile[tx][r]);
    }
}

// ---------- fc1: h1b[pstart+i][j] = relu( x[rows[i]]·W1 + b1 ), bf16 MFMA ----------
__launch_bounds__(256)
__global__ void k_fc1m(const float* __restrict__ x, const ushort* __restrict__ w1b,
                       const float* __restrict__ fc1t, const int* __restrict__ meta,
                       ushort* __restrict__ h1b) {
    const int t = blockIdx.x;
    if (t >= meta[META_NTILES]) return;
    const int L      = meta[META_TILES + 3 * t + 0];
    const int pstart = meta[META_TILES + 3 * t + 1];
    const int nrows  = meta[META_TILES + 3 * t + 2];
    const int col0   = blockIdx.y * 64;
    const ushort* __restrict__ W = w1b + (size_t)L * HIDDEN * KP1 + (size_t)col0 * KP1;

    __shared__ int rows[TB];
    __shared__ __align__(16) ushort As[64][72];   // [row][k], 144B stride: 16B-aligned, 2-way banks
    __shared__ __align__(16) ushort Bs[64][72];   // [n][k]

    const int tid = threadIdx.x;
    if (tid < TB) rows[tid] = (tid < nrows) ? meta[META_PERM + pstart + tid] : -1;
    __syncthreads();

    const int sr = tid >> 2, sc = tid & 3;        // staging: row 0..63, chunk-of-16-shorts 0..3
    const int lane = tid & 63, wv = tid >> 6;
    const int qd = lane >> 4, ln16 = lane & 15;

    const int arow = rows[sr];
    const float* __restrict__ xr = x + (size_t)(arow < 0 ? 0 : arow) * IN_DIM;
    const uint4* __restrict__ bgp = (const uint4*)(W + (size_t)sr * KP1);

    float4e acc[4] = {};

    for (int k0 = 0; k0 < KP1; k0 += BK) {
        // A: 16 floats at k = k0 + sc*16, convert to bf16
        const int ka = k0 + sc * 16;
        float4 a0 = make_float4(0.f, 0.f, 0.f, 0.f), a1 = a0, a2 = a0, a3 = a0;
        if (arow >= 0) {
            if (ka      < IN_DIM) a0 = *(const float4*)(xr + ka);
            if (ka + 4  < IN_DIM) a1 = *(const float4*)(xr + ka + 4);
            if (ka + 8  < IN_DIM) a2 = *(const float4*)(xr + ka + 8);
            if (ka + 12 < IN_DIM) a3 = *(const float4*)(xr + ka + 12);
        }
        // B: 32 bytes (2x uint4) of pre-converted bf16
        uint4 b0 = bgp[(k0 >> 3) + sc * 2 + 0];
        uint4 b1 = bgp[(k0 >> 3) + sc * 2 + 1];

        ushort av[16];
        av[0]=f2b(a0.x); av[1]=f2b(a0.y); av[2]=f2b(a0.z); av[3]=f2b(a0.w);
        av[4]=f2b(a1.x); av[5]=f2b(a1.y); av[6]=f2b(a1.z); av[7]=f2b(a1.w);
        av[8]=f2b(a2.x); av[9]=f2b(a2.y); av[10]=f2b(a2.z); av[11]=f2b(a2.w);
        av[12]=f2b(a3.x); av[13]=f2b(a3.y); av[14]=f2b(a3.z); av[15]=f2b(a3.w);
        *(uint4*)&As[sr][sc * 16 + 0] = *(const uint4*)&av[0];
        *(uint4*)&As[sr][sc * 16 + 8] = *(const uint4*)&av[8];
        *(uint4*)&Bs[sr][sc * 16 + 0] = b0;
        *(uint4*)&Bs[sr][sc * 16 + 8] = b1;
        __syncthreads();
#pragma unroll
        for (int s = 0; s < 2; ++s) {
            short8 a = *(const short8*)&As[wv * 16 + ln16][s * 32 + qd * 8];
#pragma unroll
            for (int nt = 0; nt < 4; ++nt) {
                short8 b = *(const short8*)&Bs[nt * 16 + ln16][s * 32 + qd * 8];
                acc[nt] = __builtin_amdgcn_mfma_f32_16x16x32_bf16(a, b, acc[nt], 0, 0, 0);
            }
        }
        __syncthreads();
    }

    const float* __restrict__ bias = fc1t + (size_t)L * FC1_STRIDE + (size_t)IN_DIM * HIDDEN + col0;
#pragma unroll
    for (int nt = 0; nt < 4; ++nt) {
        const int c = nt * 16 + ln16;
        const float bs = bias[c];
#pragma unroll
        for (int i = 0; i < 4; ++i) {
            const int r = wv * 16 + qd * 4 + i;
            if (r < nrows)
                h1b[(size_t)(pstart + r) * HIDDEN + col0 + c] = f2b(fmaxf(acc[nt][i] + bs, 0.f));
        }
    }
}

// ---------- fc2: out[rows[i]][j] = sigmoid( h1[i]·W2 + b2 ), bf16 MFMA ----------
__launch_bounds__(256)
__global__ void k_fc2m(const ushort* __restrict__ h1b, const ushort* __restrict__ w2b,
                       const float* __restrict__ fc2t, const int* __restrict__ meta,
                       float* __restrict__ out) {
    const int t = blockIdx.x;
    if (t >= meta[META_NTILES]) return;
    const int L      = meta[META_TILES + 3 * t + 0];
    const int pstart = meta[META_TILES + 3 * t + 1];
    const int nrows  = meta[META_TILES + 3 * t + 2];
    const int col0   = blockIdx.y * 64;
    const ushort* __restrict__ W = w2b + (size_t)L * STYLE * HIDDEN + (size_t)col0 * HIDDEN;

    __shared__ int rows[TB];
    __shared__ __align__(16) ushort As[64][72];
    __shared__ __align__(16) ushort Bs[64][72];

    const int tid = threadIdx.x;
    if (tid < TB) rows[tid] = (tid < nrows) ? meta[META_PERM + pstart + tid] : -1;
    __syncthreads();

    const int sr = tid >> 2, sc = tid & 3;
    const int lane = tid & 63, wv = tid >> 6;
    const int qd = lane >> 4, ln16 = lane & 15;

    const bool aval = (sr < nrows);
    const uint4* __restrict__ agp = (const uint4*)(h1b + (size_t)(pstart + (aval ? sr : 0)) * HIDDEN);
    const uint4* __restrict__ bgp = (const uint4*)(W + (size_t)sr * HIDDEN);

    float4e acc[4] = {};

    for (int k0 = 0; k0 < HIDDEN; k0 += BK) {
        uint4 a0 = make_uint4(0u, 0u, 0u, 0u), a1 = a0;
        if (aval) {
            a0 = agp[(k0 >> 3) + sc * 2 + 0];
            a1 = agp[(k0 >> 3) + sc * 2 + 1];
        }
        uint4 b0 = bgp[(k0 >> 3) + sc * 2 + 0];
        uint4 b1 = bgp[(k0 >> 3) + sc * 2 + 1];
        *(uint4*)&As[sr][sc * 16 + 0] = a0;
        *(uint4*)&As[sr][sc * 16 + 8] = a1;
        *(uint4*)&Bs[sr][sc * 16 + 0] = b0;
        *(uint4*)&Bs[sr][sc * 16 + 8] = b1;
        __syncthreads();
#pragma unroll
        for (int s = 0; s < 2; ++s) {
            short8 a = *(const short8*)&As[wv * 16 + ln16][s * 32 + qd * 8];
#pragma unroll
            for (int nt = 0; nt < 4; ++nt) {
                short8 b = *(const short8*)&Bs[nt * 16 + ln16][s * 32 + qd * 8];
                acc[nt] = __builtin_amdgcn_mfma_f32_16x16x32_bf16(a, b, acc[nt], 0, 0, 0);
            }
        }
        __syncthreads();
    }

    const float* __restrict__ bias = fc2t + (size_t)L * FC2_STRIDE + (size_t)HIDDEN * STYLE + col0;
#pragma unroll
    for (int nt = 0; nt < 4; ++nt) {
        const int c = nt * 16 + ln16;
        const float bs = bias[c];
#pragma unroll
        for (int i = 0; i < 4; ++i) {
            const int r = wv * 16 + qd * 4 + i;
            if (r < nrows) {
                const int orow = rows[r];
                out[(size_t)orow * STYLE + col0 + c] = 1.f / (1.f + __expf(-(acc[nt][i] + bs)));
            }
        }
    }
}

// ---------- fallback (ws too small): fused, slow but correct ----------
__launch_bounds__(256)
__global__ void k_naive(const float* __restrict__ x, const int* __restrict__ m,
                        const float* __restrict__ fc1t, const float* __restrict__ fc2t,
                        float* __restrict__ out) {
    __shared__ float xs[IN_DIM];
    __shared__ float h1[HIDDEN];
    const int b = blockIdx.x, tid = threadIdx.x, L = m[b];
    for (int k = tid; k < IN_DIM; k += 256) xs[k] = x[(size_t)b * IN_DIM + k];
    __syncthreads();
    const float* __restrict__ W1 = fc1t + (size_t)L * FC1_STRIDE;
    for (int j = tid; j < HIDDEN; j += 256) {
        float acc = W1[(size_t)IN_DIM * HIDDEN + j];
        for (int k = 0; k < IN_DIM; ++k) acc = fmaf(xs[k], W1[(size_t)k * HIDDEN + j], acc);
        h1[j] = fmaxf(acc, 0.f);
    }
    __syncthreads();
    const float* __restrict__ W2 = fc2t + (size_t)L * FC2_STRIDE;
    for (int j = tid; j < STYLE; j += 256) {
        float acc = W2[(size_t)HIDDEN * STYLE + j];
        for (int k = 0; k < HIDDEN; ++k) acc = fmaf(h1[k], W2[(size_t)k * STYLE + j], acc);
        out[(size_t)b * STYLE + j] = 1.f / (1.f + __expf(-acc));
    }
}

extern "C" void kernel_launch(void* const* d_in, const int* in_sizes, int n_in,
                              void* d_out, int out_size, void* d_ws, size_t ws_size,
                              hipStream_t stream) {
    const float* x    = (const float*)d_in[0];
    const int*   m    = (const int*)d_in[1];
    const float* fc1t = (const float*)d_in[2];
    const float* fc2t = (const float*)d_in[3];
    float* out = (float*)d_out;

    if (ws_size >= BF16_NEED) {
        int*    meta = (int*)d_ws;
        ushort* w1b  = (ushort*)((char*)d_ws + W1B_OFF);
        ushort* w2b  = (ushort*)((char*)d_ws + W2B_OFF);
        ushort* h1b  = (ushort*)((char*)d_ws + H1B_OFF);

        k_prep<<<1 + W1_BLOCKS + W2_BLOCKS, 256, 0, stream>>>(m, fc1t, fc2t, meta, w1b, w2b);
        k_fc1m<<<dim3(MAX_TILES, HIDDEN / 64), 256, 0, stream>>>(x, w1b, fc1t, meta, h1b);
        k_fc2m<<<dim3(MAX_TILES, STYLE / 64), 256, 0, stream>>>(h1b, w2b, fc2t, meta, out);
    } else {
        k_naive<<<BATCH, 256, 0, stream>>>(x, m, fc1t, fc2t, out);
    }
}